// Round 8
// baseline (1112.912 us; speedup 1.0000x reference)
//
#include <hip/hip_runtime.h>
#include <hip/hip_bf16.h>

#define N_NODES 50000
#define N_EDGES 800000
#define D 128
#define N_ETYPES 4
#define N_STEPS 8
#define B_GRAPHS 50
#define HID 256
#define POOL_SPLIT 16
#define SCAN_B 196   // ceil(50000/256)
#define NPB 16       // nodes per k_step block; 50000 = 3125 * 16 exactly

typedef __attribute__((ext_vector_type(8))) short short8;
typedef __attribute__((ext_vector_type(4))) float f32x4;
typedef __attribute__((ext_vector_type(4))) unsigned uint4v;

static __device__ __forceinline__ unsigned short f2bf(float f) {
    union { float f; unsigned u; } v; v.f = f;
    unsigned r = v.u + 0x7FFF + ((v.u >> 16) & 1);
    return (unsigned short)(r >> 16);
}
static __device__ __forceinline__ unsigned pk2(float a, float b) {
    return (unsigned)f2bf(a) | ((unsigned)f2bf(b) << 16);
}
static __device__ __forceinline__ float bf2f_u(unsigned s) {  // low 16 bits
    union { unsigned u; float f; } v; v.u = s << 16;
    return v.f;
}
static __device__ __forceinline__ float fsigmoid(float x) {
    return 1.f / (1.f + __expf(-x));
}
static __device__ __forceinline__ float ftanh(float x) {
    return 2.f / (1.f + __expf(-2.f * x)) - 1.f;
}

// ---------------- init: h_bf = bf16(node_features) ----------------
__global__ void k_init_h(const float* __restrict__ nf, unsigned short* __restrict__ hbf) {
    int i = blockIdx.x * blockDim.x + threadIdx.x;
    if (i < N_NODES * D) hbf[i] = f2bf(nf[i]);
}

// ---------------- CSR build ----------------
__global__ void k_hist(const int* __restrict__ dst, int* __restrict__ deg) {
    int e = blockIdx.x * blockDim.x + threadIdx.x;
    if (e < N_EDGES) atomicAdd(&deg[dst[e]], 1);
}

__global__ __launch_bounds__(256) void k_scan1(const int* __restrict__ deg,
                                               int* __restrict__ bsum) {
    __shared__ int tmp[256];
    int t = threadIdx.x;
    int i = blockIdx.x * 256 + t;
    tmp[t] = (i < N_NODES) ? deg[i] : 0;
    __syncthreads();
    for (int s = 128; s > 0; s >>= 1) {
        if (t < s) tmp[t] += tmp[t + s];
        __syncthreads();
    }
    if (t == 0) bsum[blockIdx.x] = tmp[0];
}

__global__ __launch_bounds__(256) void k_scan2(const int* __restrict__ bsum,
                                               int* __restrict__ bpfx,
                                               int* __restrict__ rowptr) {
    __shared__ int part[256];
    int t = threadIdx.x;
    int v = (t < SCAN_B) ? bsum[t] : 0;
    part[t] = v;
    __syncthreads();
    for (int off = 1; off < 256; off <<= 1) {
        int u = (t >= off) ? part[t - off] : 0;
        __syncthreads();
        part[t] += u;
        __syncthreads();
    }
    if (t < SCAN_B) bpfx[t] = part[t] - v;  // exclusive
    if (t == SCAN_B - 1) rowptr[N_NODES] = part[t];
}

__global__ __launch_bounds__(256) void k_scan3(const int* __restrict__ deg,
                                               const int* __restrict__ bpfx,
                                               int* __restrict__ rowptr,
                                               int* __restrict__ cursor) {
    __shared__ int part[256];
    int t = threadIdx.x;
    int i = blockIdx.x * 256 + t;
    int v = (i < N_NODES) ? deg[i] : 0;
    part[t] = v;
    __syncthreads();
    for (int off = 1; off < 256; off <<= 1) {
        int u = (t >= off) ? part[t - off] : 0;
        __syncthreads();
        part[t] += u;
        __syncthreads();
    }
    if (i < N_NODES) {
        int rp = bpfx[blockIdx.x] + part[t] - v;
        rowptr[i] = rp;
        cursor[i] = rp;
    }
}

__global__ void k_fill(const int* __restrict__ src, const int* __restrict__ dst,
                       const int* __restrict__ et, int* __restrict__ cursor,
                       int* __restrict__ epack) {
    int e = blockIdx.x * blockDim.x + threadIdx.x;
    if (e < N_EDGES) {
        int slot = atomicAdd(&cursor[dst[e]], 1);
        epack[slot] = src[e] | (et[e] << 16);  // src < 50000 < 2^16
    }
}

// ---------------- weight pre-pack into MFMA B-fragment layouts (bf16) --------
// Pmsg (Wstack, K=512, N=128): frag f = nt*16 + kc (nt<8, kc<16);
//   idx = (f*64 + l)*8 + i ; k = kc*32 + (l>>4)*8 + i ; n = nt*16 + (l&15)
// Pih/Phh (K=128, N=384): frag f = (p*8+nt)*4 + c ; k = c*32 + (l>>4)*8 + i ; B[k][n]=W[n][k]
__global__ void k_pack(const float* __restrict__ Wmsg, const float* __restrict__ Wih,
                       const float* __restrict__ Whh, unsigned short* __restrict__ Pmsg,
                       unsigned short* __restrict__ Pih, unsigned short* __restrict__ Phh) {
    int bt = blockIdx.x;  // 0..319
    int l = threadIdx.x;  // 0..63
    if (bt < 128) {  // Pmsg frag f = bt
        int nt = bt >> 4, kc = bt & 15;
        int n = nt * 16 + (l & 15);
        unsigned short* out = Pmsg + (((size_t)bt * 64 + l) * 8);
#pragma unroll
        for (int i = 0; i < 8; ++i) {
            int k = kc * 32 + ((l >> 4) << 3) + i;
            out[i] = f2bf(Wmsg[(size_t)(k >> 7) * (D * D) + (k & 127) * D + n]);
        }
        return;
    }
    const float* src;
    unsigned short* dstp;
    int id;
    if (bt < 224) { id = bt - 128; src = Wih; dstp = Pih; }
    else          { id = bt - 224; src = Whh; dstp = Phh; }
    int nt = id >> 2, c = id & 3;
    int n = nt * 16 + (l & 15);
    unsigned short* out = dstp + (((size_t)(nt * 4 + c) * 64 + l) * 8);
#pragma unroll
    for (int i = 0; i < 8; ++i) {
        int k = c * 32 + ((l >> 4) << 3) + i;
        out[i] = f2bf(src[n * D + k]);
    }
}

// ---------------- tiny gate-bias table: gb4[col] = {br, bz, bin, bhn} -------
__global__ void k_pack_bias(const float* __restrict__ bih, const float* __restrict__ bhh,
                            float4* __restrict__ gb4) {
    int c = threadIdx.x;  // 0..127
    float4 g;
    g.x = bih[c] + bhh[c];              // r gate combined bias
    g.y = bih[128 + c] + bhh[128 + c];  // z gate combined bias
    g.z = bih[256 + c];                 // n gate input bias
    g.w = bhh[256 + c];                 // n gate hidden bias
    gb4[c] = g;
}

// ============= fused step: gather + a-GEMM + GRU, one kernel ================
// Block = 16 nodes, 4 waves. LDS: swizzled S-tile [16][512] bf16 (16KB) +
// swizzled a-tile [16][128] bf16 (4KB) + deg[16] uint4. Two barriers total.
// h double-buffered: reads hold, writes hnew (no intra-step race).
__global__ __launch_bounds__(256) void k_step(const unsigned short* __restrict__ hold,
                                              unsigned short* __restrict__ hnew,
                                              const int* __restrict__ rowptr,
                                              const int* __restrict__ epack,
                                              const unsigned short* __restrict__ Pmsg,
                                              const unsigned short* __restrict__ Pih,
                                              const unsigned short* __restrict__ Phh,
                                              const float* __restrict__ bmsg,
                                              const float4* __restrict__ gb4) {
    __shared__ unsigned short Sh[NPB * 512];  // 16 KB, XOR-swizzled rows
    __shared__ unsigned short Ah[NPB * 128];  // 4 KB, XOR-swizzled rows
    __shared__ uint4v Dg[NPB];
    int tid = threadIdx.x, w = tid >> 6, l = tid & 63;
    int lr = l & 15, kb = l >> 4;
    int nb = blockIdx.x * NPB;

    // ---- phase 1: gather (each wave: 4 nodes; lane l covers d = 2l, 2l+1) ----
    for (int q = 0; q < 4; ++q) {
        int n = w * 4 + q;       // local node 0..15
        int v = nb + n;          // global node (always < N_NODES)
        int lo = rowptr[v], hi = rowptr[v + 1];
        float a00 = 0.f, a01 = 0.f, a10 = 0.f, a11 = 0.f;
        float a20 = 0.f, a21 = 0.f, a30 = 0.f, a31 = 0.f;
        unsigned c0 = 0, c1 = 0, c2 = 0, c3 = 0;
        int i = lo;
        for (; i + 4 <= hi; i += 4) {
            int e0 = epack[i], e1 = epack[i + 1], e2 = epack[i + 2], e3 = epack[i + 3];
            unsigned x0 = *(const unsigned*)(hold + ((size_t)(e0 & 0xFFFF) << 7) + 2 * l);
            unsigned x1 = *(const unsigned*)(hold + ((size_t)(e1 & 0xFFFF) << 7) + 2 * l);
            unsigned x2 = *(const unsigned*)(hold + ((size_t)(e2 & 0xFFFF) << 7) + 2 * l);
            unsigned x3 = *(const unsigned*)(hold + ((size_t)(e3 & 0xFFFF) << 7) + 2 * l);
#define ACC_EDGE(e, x)                                                        \
            {                                                                 \
                int t_ = (e) >> 16;                                           \
                float lo_ = bf2f_u((x) & 0xFFFF), hi_ = bf2f_u((x) >> 16);    \
                if (t_ == 0)      { a00 += lo_; a01 += hi_; c0++; }           \
                else if (t_ == 1) { a10 += lo_; a11 += hi_; c1++; }           \
                else if (t_ == 2) { a20 += lo_; a21 += hi_; c2++; }           \
                else              { a30 += lo_; a31 += hi_; c3++; }           \
            }
            ACC_EDGE(e0, x0) ACC_EDGE(e1, x1) ACC_EDGE(e2, x2) ACC_EDGE(e3, x3)
        }
        for (; i < hi; ++i) {
            int e0 = epack[i];
            unsigned x0 = *(const unsigned*)(hold + ((size_t)(e0 & 0xFFFF) << 7) + 2 * l);
            ACC_EDGE(e0, x0)
        }
#undef ACC_EDGE
        // swizzled LDS write: logical byte b in row n stored at b ^ ((n&7)<<4)
        unsigned swz = (unsigned)((n & 7) << 4);
        char* rowp = (char*)Sh + n * 1024;
        *(unsigned*)(rowp + ((4 * l) ^ swz))        = pk2(a00, a01);
        *(unsigned*)(rowp + ((256 + 4 * l) ^ swz))  = pk2(a10, a11);
        *(unsigned*)(rowp + ((512 + 4 * l) ^ swz))  = pk2(a20, a21);
        *(unsigned*)(rowp + ((768 + 4 * l) ^ swz))  = pk2(a30, a31);
        if (l == 0) { uint4v dgv = {c0, c1, c2, c3}; Dg[n] = dgv; }
    }
    __syncthreads();

    // ---- phase 2: a = S @ Wstack + deg-weighted bmsg  (wave w: ntiles w, w+4) ----
    {
        f32x4 acc0 = {0.f, 0.f, 0.f, 0.f}, acc1 = {0.f, 0.f, 0.f, 0.f};
        const short8* Bp = (const short8*)Pmsg;
        unsigned rswz = (unsigned)((lr & 7) << 4);
#pragma unroll
        for (int kc = 0; kc < 16; ++kc) {
            short8 af = *(const short8*)((const char*)Sh + lr * 1024 +
                                         (((unsigned)(kc * 64 + kb * 16)) ^ rswz));
            short8 b0 = Bp[(size_t)(w * 16 + kc) * 64 + l];
            short8 b1 = Bp[(size_t)((w + 4) * 16 + kc) * 64 + l];
            acc0 = __builtin_amdgcn_mfma_f32_16x16x32_bf16(af, b0, acc0, 0, 0, 0);
            acc1 = __builtin_amdgcn_mfma_f32_16x16x32_bf16(af, b1, acc1, 0, 0, 0);
        }
#pragma unroll
        for (int t = 0; t < 2; ++t) {
            int nt = w + t * 4;
            int col = nt * 16 + lr;
            float b0 = bmsg[col], b1 = bmsg[128 + col], b2 = bmsg[256 + col], b3 = bmsg[384 + col];
            f32x4 acc = t ? acc1 : acc0;
#pragma unroll
            for (int j = 0; j < 4; ++j) {
                int row = kb * 4 + j;  // local 0..15
                uint4v dgv = Dg[row];
                float av = acc[j] + (float)dgv.x * b0 + (float)dgv.y * b1 +
                           (float)dgv.z * b2 + (float)dgv.w * b3;
                *(unsigned short*)((char*)Ah + row * 256 +
                                   (((unsigned)(2 * col)) ^ ((unsigned)((row & 7) << 4)))) = f2bf(av);
            }
        }
    }
    __syncthreads();

    // ---- phase 3: gates (wave w: ntiles w, w+4) ----
    {
        const short8* hrow = (const short8*)(hold + (size_t)(nb + lr) * D);
        short8 afh[4];
#pragma unroll
        for (int c = 0; c < 4; ++c) afh[c] = hrow[c * 4 + kb];
        f32x4 racc[2], zacc[2], giacc[2], ghacc[2];
#pragma unroll
        for (int t = 0; t < 2; ++t) {
            racc[t] = (f32x4){0.f, 0.f, 0.f, 0.f};
            zacc[t] = (f32x4){0.f, 0.f, 0.f, 0.f};
            giacc[t] = (f32x4){0.f, 0.f, 0.f, 0.f};
            ghacc[t] = (f32x4){0.f, 0.f, 0.f, 0.f};
        }
        const short8* Bi = (const short8*)Pih;
        const short8* Bh = (const short8*)Phh;
        unsigned rswz = (unsigned)((lr & 7) << 4);
#pragma unroll
        for (int c = 0; c < 4; ++c) {
            short8 afa = *(const short8*)((const char*)Ah + lr * 256 +
                                          (((unsigned)(c * 64 + kb * 16)) ^ rswz));
#pragma unroll
            for (int t = 0; t < 2; ++t) {
                int nt = w + t * 4;
                short8 bir = Bi[(size_t)((0 + nt) * 4 + c) * 64 + l];
                short8 bhr = Bh[(size_t)((0 + nt) * 4 + c) * 64 + l];
                short8 biz = Bi[(size_t)((8 + nt) * 4 + c) * 64 + l];
                short8 bhz = Bh[(size_t)((8 + nt) * 4 + c) * 64 + l];
                short8 bin = Bi[(size_t)((16 + nt) * 4 + c) * 64 + l];
                short8 bhn = Bh[(size_t)((16 + nt) * 4 + c) * 64 + l];
                racc[t] = __builtin_amdgcn_mfma_f32_16x16x32_bf16(afa, bir, racc[t], 0, 0, 0);
                racc[t] = __builtin_amdgcn_mfma_f32_16x16x32_bf16(afh[c], bhr, racc[t], 0, 0, 0);
                zacc[t] = __builtin_amdgcn_mfma_f32_16x16x32_bf16(afa, biz, zacc[t], 0, 0, 0);
                zacc[t] = __builtin_amdgcn_mfma_f32_16x16x32_bf16(afh[c], bhz, zacc[t], 0, 0, 0);
                giacc[t] = __builtin_amdgcn_mfma_f32_16x16x32_bf16(afa, bin, giacc[t], 0, 0, 0);
                ghacc[t] = __builtin_amdgcn_mfma_f32_16x16x32_bf16(afh[c], bhn, ghacc[t], 0, 0, 0);
            }
        }
#pragma unroll
        for (int t = 0; t < 2; ++t) {
            int nt = w + t * 4;
            int col = nt * 16 + lr;
            float4 gb = gb4[col];
#pragma unroll
            for (int j = 0; j < 4; ++j) {
                int row = nb + kb * 4 + j;
                float rr = fsigmoid(racc[t][j] + gb.x);
                float zz = fsigmoid(zacc[t][j] + gb.y);
                float nn = ftanh(giacc[t][j] + gb.z + rr * (ghacc[t][j] + gb.w));
                size_t idx = (size_t)row * D + col;
                float hv = bf2f_u(hold[idx]);
                hnew[idx] = f2bf((1.f - zz) * nn + zz * hv);
            }
        }
    }
}

// ---------------- pool phase 1: partial row-sums (bf16 h) ----------------
__global__ __launch_bounds__(256) void k_pool1(const unsigned short* __restrict__ hbf,
                                               const int* __restrict__ counts,
                                               float* __restrict__ partial) {
    __shared__ float tmp[256];
    int g = blockIdx.x / POOL_SPLIT;
    int j = blockIdx.x % POOL_SPLIT;
    int t = threadIdx.x;
    int offset = 0;
    for (int i = 0; i < g; ++i) offset += counts[i];
    int cnt = counts[g];
    int d = t & 127, half = t >> 7;
    float acc = 0.f;
    for (int r = 2 * j + half; r < cnt; r += 2 * POOL_SPLIT)
        acc += bf2f_u(hbf[(size_t)(offset + r) * D + d]);
    tmp[t] = acc;
    __syncthreads();
    if (t < D) partial[(size_t)(g * POOL_SPLIT + j) * D + t] = tmp[t] + tmp[t + 128];
}

// ---------------- pool phase 2: combine + MLP + sigmoid ----------------
__global__ __launch_bounds__(256) void k_pool2(const float* __restrict__ partial,
                                               const int* __restrict__ counts,
                                               const float* __restrict__ W1,
                                               const float* __restrict__ b1,
                                               const float* __restrict__ W2,
                                               const float* __restrict__ b2,
                                               float* __restrict__ out) {
    __shared__ float pooled[D];
    __shared__ float xh[HID];
    int g = blockIdx.x;
    int t = threadIdx.x;
    int cnt = counts[g];
    if (t < D) {
        float s = 0.f;
#pragma unroll
        for (int j = 0; j < POOL_SPLIT; ++j)
            s += partial[(size_t)(g * POOL_SPLIT + j) * D + t];
        pooled[t] = s / (float)cnt;
    }
    __syncthreads();
    float x = b1[t];
    for (int k = 0; k < D; ++k) x += pooled[k] * W1[k * HID + t];
    x = fmaxf(x, 0.f);
    xh[t] = x * W2[t];
    __syncthreads();
    for (int s = 128; s > 0; s >>= 1) {
        if (t < s) xh[t] += xh[t + s];
        __syncthreads();
    }
    if (t == 0) out[g] = 1.f / (1.f + __expf(-(xh[0] + b2[0])));
}

extern "C" void kernel_launch(void* const* d_in, const int* in_sizes, int n_in,
                              void* d_out, int out_size, void* d_ws, size_t ws_size,
                              hipStream_t stream) {
    const float* nf   = (const float*)d_in[0];
    const int* esrc   = (const int*)d_in[1];
    const int* edst   = (const int*)d_in[2];
    const int* etyp   = (const int*)d_in[3];
    const int* counts = (const int*)d_in[4];
    const float* Wmsg = (const float*)d_in[5];
    const float* bmsg = (const float*)d_in[6];   // [4][128] flat == [512] concat
    const float* Wih  = (const float*)d_in[7];
    const float* Whh  = (const float*)d_in[8];
    const float* bih  = (const float*)d_in[9];
    const float* bhh  = (const float*)d_in[10];
    const float* W1   = (const float*)d_in[11];
    const float* b1   = (const float*)d_in[12];
    const float* W2   = (const float*)d_in[13];
    const float* b2   = (const float*)d_in[14];
    float* out = (float*)d_out;

    char* ws = (char*)d_ws;
    size_t off = 0;
    auto alloc = [&](size_t bytes) {
        void* p = ws + off;
        off = (off + bytes + 255) & ~(size_t)255;
        return p;
    };
    unsigned short* hbf0 = (unsigned short*)alloc((size_t)N_NODES * D * 2);
    unsigned short* hbf1 = (unsigned short*)alloc((size_t)N_NODES * D * 2);
    unsigned short* Pmsg = (unsigned short*)alloc(128 * 64 * 8 * 2);
    unsigned short* Pih  = (unsigned short*)alloc(24 * 4 * 64 * 8 * 2);
    unsigned short* Phh  = (unsigned short*)alloc(24 * 4 * 64 * 8 * 2);
    float* gb4 = (float*)alloc(128 * 16);
    int* deg    = (int*)alloc((size_t)N_NODES * 4);
    int* rowptr = (int*)alloc((size_t)(N_NODES + 1) * 4);
    int* cursor = (int*)alloc((size_t)N_NODES * 4);
    int* epack  = (int*)alloc((size_t)N_EDGES * 4);
    float* partial = (float*)alloc((size_t)B_GRAPHS * POOL_SPLIT * D * 4);
    int* bsum = (int*)alloc(SCAN_B * 4);
    int* bpfx = (int*)alloc(SCAN_B * 4);

    hipMemsetAsync(deg, 0, (size_t)N_NODES * 4, stream);
    k_init_h<<<(N_NODES * D) / 256, 256, 0, stream>>>(nf, hbf0);
    k_hist<<<N_EDGES / 256, 256, 0, stream>>>(edst, deg);
    k_scan1<<<SCAN_B, 256, 0, stream>>>(deg, bsum);
    k_scan2<<<1, 256, 0, stream>>>(bsum, bpfx, rowptr);
    k_scan3<<<SCAN_B, 256, 0, stream>>>(deg, bpfx, rowptr, cursor);
    k_fill<<<N_EDGES / 256, 256, 0, stream>>>(esrc, edst, etyp, cursor, epack);
    k_pack<<<320, 64, 0, stream>>>(Wmsg, Wih, Whh, Pmsg, Pih, Phh);
    k_pack_bias<<<1, 128, 0, stream>>>(bih, bhh, (float4*)gb4);

    const int step_blocks = N_NODES / NPB;  // 3125
    for (int s = 0; s < N_STEPS; ++s) {
        const unsigned short* hold = (s & 1) ? hbf1 : hbf0;
        unsigned short* hnew       = (s & 1) ? hbf0 : hbf1;
        k_step<<<step_blocks, 256, 0, stream>>>(hold, hnew, rowptr, epack,
                                                Pmsg, Pih, Phh, bmsg,
                                                (const float4*)gb4);
    }
    // after 8 steps (even), final h is in hbf0
    k_pool1<<<B_GRAPHS * POOL_SPLIT, 256, 0, stream>>>(hbf0, counts, partial);
    k_pool2<<<B_GRAPHS, 256, 0, stream>>>(partial, counts, W1, b1, W2, b2, out);
}

// Round 9
// 1054.380 us; speedup vs baseline: 1.0555x; 1.0555x over previous
//
#include <hip/hip_runtime.h>
#include <hip/hip_bf16.h>

#define N_NODES 50000
#define N_EDGES 800000
#define D 128
#define N_ETYPES 4
#define N_STEPS 8
#define B_GRAPHS 50
#define HID 256
#define POOL_SPLIT 16
#define N4 (N_NODES * N_ETYPES)          // 200000 per-(node,type) segments
#define SCAN_B4 ((N4 + 255) / 256)       // 782

typedef __attribute__((ext_vector_type(8))) short short8;
typedef __attribute__((ext_vector_type(4))) float f32x4;
typedef __attribute__((ext_vector_type(4))) unsigned uint4v;
typedef __attribute__((ext_vector_type(4))) int int4v;

static __device__ __forceinline__ unsigned short f2bf(float f) {
    union { float f; unsigned u; } v; v.f = f;
    unsigned r = v.u + 0x7FFF + ((v.u >> 16) & 1);
    return (unsigned short)(r >> 16);
}
static __device__ __forceinline__ unsigned pk2(float a, float b) {
    return (unsigned)f2bf(a) | ((unsigned)f2bf(b) << 16);
}
static __device__ __forceinline__ float bf2f_u(unsigned s) {  // low 16 bits
    union { unsigned u; float f; } v; v.u = s << 16;
    return v.f;
}
static __device__ __forceinline__ float bflo(unsigned x) {  // low bf16 -> f32
    union { unsigned u; float f; } v; v.u = x << 16;
    return v.f;
}
static __device__ __forceinline__ float bfhi(unsigned x) {  // high bf16 -> f32
    union { unsigned u; float f; } v; v.u = x & 0xFFFF0000u;
    return v.f;
}
static __device__ __forceinline__ float fsigmoid(float x) {
    return 1.f / (1.f + __expf(-x));
}
static __device__ __forceinline__ float ftanh(float x) {
    return 2.f / (1.f + __expf(-2.f * x)) - 1.f;
}

// ---------------- init: h_bf = bf16(node_features) ----------------
__global__ void k_init_h(const float* __restrict__ nf, unsigned short* __restrict__ hbf) {
    int i = blockIdx.x * blockDim.x + threadIdx.x;
    if (i < N_NODES * D) hbf[i] = f2bf(nf[i]);
}

// ---------------- CSR build over (dst, type) segments ----------------
__global__ void k_hist(const int* __restrict__ dst, const int* __restrict__ et,
                       int* __restrict__ deg4) {
    int e = blockIdx.x * blockDim.x + threadIdx.x;
    if (e < N_EDGES) atomicAdd(&deg4[dst[e] * 4 + et[e]], 1);
}

__global__ __launch_bounds__(256) void k_scan1(const int* __restrict__ deg4,
                                               int* __restrict__ bsum) {
    __shared__ int tmp[256];
    int t = threadIdx.x;
    int i = blockIdx.x * 256 + t;
    tmp[t] = (i < N4) ? deg4[i] : 0;
    __syncthreads();
    for (int s = 128; s > 0; s >>= 1) {
        if (t < s) tmp[t] += tmp[t + s];
        __syncthreads();
    }
    if (t == 0) bsum[blockIdx.x] = tmp[0];
}

__global__ __launch_bounds__(1024) void k_scan2(const int* __restrict__ bsum,
                                                int* __restrict__ bpfx,
                                                int* __restrict__ rowptr4) {
    __shared__ int part[1024];
    int t = threadIdx.x;
    int v = (t < SCAN_B4) ? bsum[t] : 0;
    part[t] = v;
    __syncthreads();
    for (int off = 1; off < 1024; off <<= 1) {
        int u = (t >= off) ? part[t - off] : 0;
        __syncthreads();
        part[t] += u;
        __syncthreads();
    }
    if (t < SCAN_B4) bpfx[t] = part[t] - v;  // exclusive
    if (t == SCAN_B4 - 1) rowptr4[N4] = part[t];  // = N_EDGES
}

__global__ __launch_bounds__(256) void k_scan3(const int* __restrict__ deg4,
                                               const int* __restrict__ bpfx,
                                               int* __restrict__ rowptr4,
                                               int* __restrict__ cursor4) {
    __shared__ int part[256];
    int t = threadIdx.x;
    int i = blockIdx.x * 256 + t;
    int v = (i < N4) ? deg4[i] : 0;
    part[t] = v;
    __syncthreads();
    for (int off = 1; off < 256; off <<= 1) {
        int u = (t >= off) ? part[t - off] : 0;
        __syncthreads();
        part[t] += u;
        __syncthreads();
    }
    if (i < N4) {
        int rp = bpfx[blockIdx.x] + part[t] - v;
        rowptr4[i] = rp;
        cursor4[i] = rp;
    }
}

// epack[slot] = src * 256 (pre-scaled byte offset into h rows)
__global__ void k_fill(const int* __restrict__ src, const int* __restrict__ dst,
                       const int* __restrict__ et, int* __restrict__ cursor4,
                       int* __restrict__ epack) {
    int e = blockIdx.x * blockDim.x + threadIdx.x;
    if (e < N_EDGES) {
        int slot = atomicAdd(&cursor4[dst[e] * 4 + et[e]], 1);
        epack[slot] = src[e] << 8;
    }
}

// ---------------- weight pre-pack into MFMA B-fragment layouts (bf16) --------
// Pmsg (Wstack, K=512, N=128): frag f = nt*16 + kc (nt<8, kc<16);
//   idx = (f*64 + l)*8 + i ; k = kc*32 + (l>>4)*8 + i ; n = nt*16 + (l&15)
// Pih/Phh (K=128, N=384): frag f = nt*4 + c (nt<24); k = c*32 + (l>>4)*8 + i ; B[k][n]=W[n][k]
__global__ void k_pack(const float* __restrict__ Wmsg, const float* __restrict__ Wih,
                       const float* __restrict__ Whh, unsigned short* __restrict__ Pmsg,
                       unsigned short* __restrict__ Pih, unsigned short* __restrict__ Phh) {
    int bt = blockIdx.x;  // 0..319
    int l = threadIdx.x;  // 0..63
    if (bt < 128) {  // Pmsg frag f = bt
        int nt = bt >> 4, kc = bt & 15;
        int n = nt * 16 + (l & 15);
        unsigned short* out = Pmsg + (((size_t)bt * 64 + l) * 8);
#pragma unroll
        for (int i = 0; i < 8; ++i) {
            int k = kc * 32 + ((l >> 4) << 3) + i;
            out[i] = f2bf(Wmsg[(size_t)(k >> 7) * (D * D) + (k & 127) * D + n]);
        }
        return;
    }
    const float* src;
    unsigned short* dstp;
    int id;
    if (bt < 224) { id = bt - 128; src = Wih; dstp = Pih; }
    else          { id = bt - 224; src = Whh; dstp = Phh; }
    int nt = id >> 2, c = id & 3;
    int n = nt * 16 + (l & 15);
    unsigned short* out = dstp + (((size_t)(nt * 4 + c) * 64 + l) * 8);
#pragma unroll
    for (int i = 0; i < 8; ++i) {
        int k = c * 32 + ((l >> 4) << 3) + i;
        out[i] = f2bf(src[n * D + k]);
    }
}

// ---------------- tiny gate-bias table: gb4[col] = {br, bz, bin, bhn} -------
__global__ void k_pack_bias(const float* __restrict__ bih, const float* __restrict__ bhh,
                            float4* __restrict__ gb4) {
    int c = threadIdx.x;  // 0..127
    float4 g;
    g.x = bih[c] + bhh[c];              // r gate combined bias
    g.y = bih[128 + c] + bhh[128 + c];  // z gate combined bias
    g.z = bih[256 + c];                 // n gate input bias
    g.w = bhh[256 + c];                 // n gate hidden bias
    gb4[c] = g;
}

// ---------------- aggregate (type-sorted, branch-free segments) --------------
// one wave per node; lane l covers d = 2l, 2l+1
__global__ __launch_bounds__(256) void k_aggregate_s(const unsigned short* __restrict__ hold,
                                                     const int* __restrict__ rowptr4,
                                                     const int* __restrict__ epack,
                                                     unsigned short* __restrict__ S) {
    int w = threadIdx.x >> 6, l = threadIdx.x & 63;
    int v = blockIdx.x * 4 + w;
    if (v >= N_NODES) return;
    int4v b = *(const int4v*)(rowptr4 + v * 4);
    int b4 = rowptr4[v * 4 + 4];
    const char* hp = (const char*)hold + 4 * l;
    unsigned* Srow = (unsigned*)(S + (size_t)v * 512);
#pragma unroll
    for (int t = 0; t < 4; ++t) {
        int i  = (t == 0) ? b.x : (t == 1) ? b.y : (t == 2) ? b.z : b.w;
        int hi = (t == 0) ? b.y : (t == 1) ? b.z : (t == 2) ? b.w : b4;
        float a0 = 0.f, a1 = 0.f;
        for (; i + 4 <= hi; i += 4) {
            int s0 = epack[i], s1 = epack[i + 1], s2 = epack[i + 2], s3 = epack[i + 3];
            unsigned x0 = *(const unsigned*)(hp + s0);
            unsigned x1 = *(const unsigned*)(hp + s1);
            unsigned x2 = *(const unsigned*)(hp + s2);
            unsigned x3 = *(const unsigned*)(hp + s3);
            a0 += bflo(x0) + bflo(x1) + bflo(x2) + bflo(x3);
            a1 += bfhi(x0) + bfhi(x1) + bfhi(x2) + bfhi(x3);
        }
        if (i + 2 <= hi) {
            int s0 = epack[i], s1 = epack[i + 1];
            unsigned x0 = *(const unsigned*)(hp + s0);
            unsigned x1 = *(const unsigned*)(hp + s1);
            a0 += bflo(x0) + bflo(x1);
            a1 += bfhi(x0) + bfhi(x1);
            i += 2;
        }
        if (i < hi) {
            unsigned x0 = *(const unsigned*)(hp + epack[i]);
            a0 += bflo(x0);
            a1 += bfhi(x0);
        }
        Srow[t * 64 + l] = pk2(a0, a1);
    }
}

// ---------------- a-GEMM (no LDS/barriers, column-split x2) ------------------
// block: 4 waves x 16 rows = 64 rows, 4 ntiles (bid&1 picks half). deg from rowptr4.
__global__ __launch_bounds__(256) void k_gemm_a(const unsigned short* __restrict__ S,
                                                const unsigned short* __restrict__ Pmsg,
                                                const int* __restrict__ rowptr4,
                                                const float* __restrict__ bmsg,
                                                unsigned short* __restrict__ abf) {
    int tid = threadIdx.x, w = tid >> 6, l = tid & 63;
    int base = (blockIdx.x >> 1) * 64 + w * 16;
    int nh = (blockIdx.x & 1) * 4;  // ntile base
    int lr = l & 15, kb = l >> 4;
    int arow = base + lr; if (arow >= N_NODES) arow = N_NODES - 1;
    const short8* Sr = (const short8*)(S + (size_t)arow * 512);
    short8 af[16];
#pragma unroll
    for (int kc = 0; kc < 16; ++kc) af[kc] = Sr[kc * 4 + kb];
    float dgf[4][4];
#pragma unroll
    for (int j = 0; j < 4; ++j) {
        int row = base + kb * 4 + j; if (row >= N_NODES) row = N_NODES - 1;
        int4v r4 = *(const int4v*)(rowptr4 + row * 4);
        int r5 = rowptr4[row * 4 + 4];
        dgf[j][0] = (float)(r4.y - r4.x);
        dgf[j][1] = (float)(r4.z - r4.y);
        dgf[j][2] = (float)(r4.w - r4.z);
        dgf[j][3] = (float)(r5 - r4.w);
    }
    const short8* Bp = (const short8*)Pmsg;  // frag f: Bp[f*64 + l]
#pragma unroll
    for (int ntp = 0; ntp < 2; ++ntp) {
        int nt0 = nh + ntp * 2;
        f32x4 acc0 = {0.f, 0.f, 0.f, 0.f}, acc1 = {0.f, 0.f, 0.f, 0.f};
#pragma unroll
        for (int kc = 0; kc < 16; ++kc) {
            short8 b0 = Bp[(size_t)((nt0 + 0) * 16 + kc) * 64 + l];
            short8 b1 = Bp[(size_t)((nt0 + 1) * 16 + kc) * 64 + l];
            acc0 = __builtin_amdgcn_mfma_f32_16x16x32_bf16(af[kc], b0, acc0, 0, 0, 0);
            acc1 = __builtin_amdgcn_mfma_f32_16x16x32_bf16(af[kc], b1, acc1, 0, 0, 0);
        }
#pragma unroll
        for (int half = 0; half < 2; ++half) {
            f32x4 acc = half ? acc1 : acc0;
            int col = (nt0 + half) * 16 + lr;
            float b0 = bmsg[col], b1 = bmsg[128 + col], b2 = bmsg[256 + col], b3 = bmsg[384 + col];
#pragma unroll
            for (int j = 0; j < 4; ++j) {
                int row = base + kb * 4 + j;
                if (row < N_NODES) {
                    float bias = dgf[j][0] * b0 + dgf[j][1] * b1 + dgf[j][2] * b2 + dgf[j][3] * b3;
                    abf[(size_t)row * D + col] = f2bf(acc[j] + bias);
                }
            }
        }
    }
}

// ---------------- fused GRU (no LDS/barriers, column-split x2, dbuf h) -------
__global__ __launch_bounds__(256) void k_gru(const unsigned short* __restrict__ abf,
                                             const unsigned short* __restrict__ hold,
                                             unsigned short* __restrict__ hnew,
                                             const unsigned short* __restrict__ Pih,
                                             const unsigned short* __restrict__ Phh,
                                             const float4* __restrict__ gb4) {
    int tid = threadIdx.x, w = tid >> 6, l = tid & 63;
    int base = (blockIdx.x >> 1) * 64 + w * 16;
    int nt0 = (blockIdx.x & 1) * 4;
    int lr = l & 15, kb = l >> 4;
    int arow = base + lr; if (arow >= N_NODES) arow = N_NODES - 1;
    const short8* ar = (const short8*)(abf + (size_t)arow * D);
    const short8* hr = (const short8*)(hold + (size_t)arow * D);
    short8 afa[4], afh[4];
#pragma unroll
    for (int c = 0; c < 4; ++c) { afa[c] = ar[c * 4 + kb]; afh[c] = hr[c * 4 + kb]; }
    const short8* Bi = (const short8*)Pih;  // frag f: Bi[f*64 + l], f = (p*8+nt)*4+c
    const short8* Bh = (const short8*)Phh;
#pragma unroll
    for (int ntl = 0; ntl < 4; ++ntl) {
        int nt = nt0 + ntl;
        f32x4 racc = {0.f, 0.f, 0.f, 0.f};
        f32x4 zacc = {0.f, 0.f, 0.f, 0.f};
        f32x4 giacc = {0.f, 0.f, 0.f, 0.f};
        f32x4 ghacc = {0.f, 0.f, 0.f, 0.f};
#pragma unroll
        for (int c = 0; c < 4; ++c) {
            short8 bir = Bi[((0 * 8 + nt) * 4 + c) * 64 + l];
            short8 bhr = Bh[((0 * 8 + nt) * 4 + c) * 64 + l];
            short8 biz = Bi[((1 * 8 + nt) * 4 + c) * 64 + l];
            short8 bhz = Bh[((1 * 8 + nt) * 4 + c) * 64 + l];
            short8 bin = Bi[((2 * 8 + nt) * 4 + c) * 64 + l];
            short8 bhn = Bh[((2 * 8 + nt) * 4 + c) * 64 + l];
            racc = __builtin_amdgcn_mfma_f32_16x16x32_bf16(afa[c], bir, racc, 0, 0, 0);
            racc = __builtin_amdgcn_mfma_f32_16x16x32_bf16(afh[c], bhr, racc, 0, 0, 0);
            zacc = __builtin_amdgcn_mfma_f32_16x16x32_bf16(afa[c], biz, zacc, 0, 0, 0);
            zacc = __builtin_amdgcn_mfma_f32_16x16x32_bf16(afh[c], bhz, zacc, 0, 0, 0);
            giacc = __builtin_amdgcn_mfma_f32_16x16x32_bf16(afa[c], bin, giacc, 0, 0, 0);
            ghacc = __builtin_amdgcn_mfma_f32_16x16x32_bf16(afh[c], bhn, ghacc, 0, 0, 0);
        }
        int col = nt * 16 + lr;
        float4 gb = gb4[col];
#pragma unroll
        for (int j = 0; j < 4; ++j) {
            int row = base + kb * 4 + j;
            if (row < N_NODES) {
                float rr = fsigmoid(racc[j] + gb.x);
                float zz = fsigmoid(zacc[j] + gb.y);
                float nn = ftanh(giacc[j] + gb.z + rr * (ghacc[j] + gb.w));
                size_t idx = (size_t)row * D + col;
                float hv = bf2f_u(hold[idx]);
                hnew[idx] = f2bf((1.f - zz) * nn + zz * hv);
            }
        }
    }
}

// ---------------- pool phase 1: partial row-sums (bf16 h) ----------------
__global__ __launch_bounds__(256) void k_pool1(const unsigned short* __restrict__ hbf,
                                               const int* __restrict__ counts,
                                               float* __restrict__ partial) {
    __shared__ float tmp[256];
    int g = blockIdx.x / POOL_SPLIT;
    int j = blockIdx.x % POOL_SPLIT;
    int t = threadIdx.x;
    int offset = 0;
    for (int i = 0; i < g; ++i) offset += counts[i];
    int cnt = counts[g];
    int d = t & 127, half = t >> 7;
    float acc = 0.f;
    for (int r = 2 * j + half; r < cnt; r += 2 * POOL_SPLIT)
        acc += bf2f_u(hbf[(size_t)(offset + r) * D + d]);
    tmp[t] = acc;
    __syncthreads();
    if (t < D) partial[(size_t)(g * POOL_SPLIT + j) * D + t] = tmp[t] + tmp[t + 128];
}

// ---------------- pool phase 2: combine + MLP + sigmoid ----------------
__global__ __launch_bounds__(256) void k_pool2(const float* __restrict__ partial,
                                               const int* __restrict__ counts,
                                               const float* __restrict__ W1,
                                               const float* __restrict__ b1,
                                               const float* __restrict__ W2,
                                               const float* __restrict__ b2,
                                               float* __restrict__ out) {
    __shared__ float pooled[D];
    __shared__ float xh[HID];
    int g = blockIdx.x;
    int t = threadIdx.x;
    int cnt = counts[g];
    if (t < D) {
        float s = 0.f;
#pragma unroll
        for (int j = 0; j < POOL_SPLIT; ++j)
            s += partial[(size_t)(g * POOL_SPLIT + j) * D + t];
        pooled[t] = s / (float)cnt;
    }
    __syncthreads();
    float x = b1[t];
    for (int k = 0; k < D; ++k) x += pooled[k] * W1[k * HID + t];
    x = fmaxf(x, 0.f);
    xh[t] = x * W2[t];
    __syncthreads();
    for (int s = 128; s > 0; s >>= 1) {
        if (t < s) xh[t] += xh[t + s];
        __syncthreads();
    }
    if (t == 0) out[g] = 1.f / (1.f + __expf(-(xh[0] + b2[0])));
}

extern "C" void kernel_launch(void* const* d_in, const int* in_sizes, int n_in,
                              void* d_out, int out_size, void* d_ws, size_t ws_size,
                              hipStream_t stream) {
    const float* nf   = (const float*)d_in[0];
    const int* esrc   = (const int*)d_in[1];
    const int* edst   = (const int*)d_in[2];
    const int* etyp   = (const int*)d_in[3];
    const int* counts = (const int*)d_in[4];
    const float* Wmsg = (const float*)d_in[5];
    const float* bmsg = (const float*)d_in[6];   // [4][128] flat == [512] concat
    const float* Wih  = (const float*)d_in[7];
    const float* Whh  = (const float*)d_in[8];
    const float* bih  = (const float*)d_in[9];
    const float* bhh  = (const float*)d_in[10];
    const float* W1   = (const float*)d_in[11];
    const float* b1   = (const float*)d_in[12];
    const float* W2   = (const float*)d_in[13];
    const float* b2   = (const float*)d_in[14];
    float* out = (float*)d_out;

    char* ws = (char*)d_ws;
    size_t off = 0;
    auto alloc = [&](size_t bytes) {
        void* p = ws + off;
        off = (off + bytes + 255) & ~(size_t)255;
        return p;
    };
    unsigned short* hbf0 = (unsigned short*)alloc((size_t)N_NODES * D * 2);
    unsigned short* hbf1 = (unsigned short*)alloc((size_t)N_NODES * D * 2);
    unsigned short* abf  = (unsigned short*)alloc((size_t)N_NODES * D * 2);
    unsigned short* S    = (unsigned short*)alloc((size_t)N_NODES * 512 * 2);
    unsigned short* Pmsg = (unsigned short*)alloc(128 * 64 * 8 * 2);
    unsigned short* Pih  = (unsigned short*)alloc(24 * 4 * 64 * 8 * 2);
    unsigned short* Phh  = (unsigned short*)alloc(24 * 4 * 64 * 8 * 2);
    float* gb4 = (float*)alloc(128 * 16);
    int* deg4    = (int*)alloc((size_t)N4 * 4);
    int* rowptr4 = (int*)alloc((size_t)(N4 + 1) * 4);
    int* cursor4 = (int*)alloc((size_t)N4 * 4);
    int* epack   = (int*)alloc((size_t)N_EDGES * 4);
    float* partial = (float*)alloc((size_t)B_GRAPHS * POOL_SPLIT * D * 4);
    int* bsum = (int*)alloc(SCAN_B4 * 4);
    int* bpfx = (int*)alloc(SCAN_B4 * 4);

    hipMemsetAsync(deg4, 0, (size_t)N4 * 4, stream);
    k_init_h<<<(N_NODES * D) / 256, 256, 0, stream>>>(nf, hbf0);
    k_hist<<<N_EDGES / 256, 256, 0, stream>>>(edst, etyp, deg4);
    k_scan1<<<SCAN_B4, 256, 0, stream>>>(deg4, bsum);
    k_scan2<<<1, 1024, 0, stream>>>(bsum, bpfx, rowptr4);
    k_scan3<<<SCAN_B4, 256, 0, stream>>>(deg4, bpfx, rowptr4, cursor4);
    k_fill<<<N_EDGES / 256, 256, 0, stream>>>(esrc, edst, etyp, cursor4, epack);
    k_pack<<<320, 64, 0, stream>>>(Wmsg, Wih, Whh, Pmsg, Pih, Phh);
    k_pack_bias<<<1, 128, 0, stream>>>(bih, bhh, (float4*)gb4);

    int ga_blocks  = 2 * ((N_NODES + 63) / 64);  // 1564 (64 rows x 64 cols)
    int gru_blocks = 2 * ((N_NODES + 63) / 64);  // 1564
    int agg_blocks = (N_NODES + 3) / 4;          // 12500
    for (int s = 0; s < N_STEPS; ++s) {
        const unsigned short* hold = (s & 1) ? hbf1 : hbf0;
        unsigned short* hnew       = (s & 1) ? hbf0 : hbf1;
        k_aggregate_s<<<agg_blocks, 256, 0, stream>>>(hold, rowptr4, epack, S);
        k_gemm_a<<<ga_blocks, 256, 0, stream>>>(S, Pmsg, rowptr4, bmsg, abf);
        k_gru<<<gru_blocks, 256, 0, stream>>>(abf, hold, hnew, Pih, Phh,
                                              (const float4*)gb4);
    }
    // after 8 steps (even), final h is in hbf0
    k_pool1<<<B_GRAPHS * POOL_SPLIT, 256, 0, stream>>>(hbf0, counts, partial);
    k_pool2<<<B_GRAPHS, 256, 0, stream>>>(partial, counts, W1, b1, W2, b2, out);
}